// Round 11
// baseline (46.538 us; speedup 1.0000x reference)
//
#include <hip/hip_runtime.h>
#include <hip/hip_fp16.h>

#define CROP_H 14
#define CROP_W 14
#define CROP_HW 196
#define CROP_HWP 98          // pair units per box
#define CROP_HWQ 49          // quad units per box
#define IMG_H 100
#define IMG_W 100
#define PLANE 10000
#define NCH 256
#define NBOX 512
#define NIMG 8
#define MAXI 8               // register-resident iterations (covers nb <= 83)

// d_ws layout: geo_sorted : uint2[NBOX*CROP_HW] (8 B per (slot,hw), sorted by image)
#define GEO_BYTES ((size_t)NBOX * CROP_HW * 8)
#define WS_NEED   GEO_BYTES

// ---------------- Kernel 1: geometry, self-computed stable slot, n embedded ------
// pk bits: [13:0]=tl slot (y0*100+x0), [15]=dy, [16]=valid, [25:17]=n
// (dx clamp absorbed by shifted-pair LDS layout in the main kernel)
__global__ __launch_bounds__(256) void geom_kernel(
    const float* __restrict__ boxes, const int* __restrict__ box_ind,
    uint2* __restrict__ geo)
{
    __shared__ int s_lt[8], s_eq[8];

    const int n    = blockIdx.x;
    const int t    = threadIdx.x;
    const int lane = t & 63;
    const int wv   = t >> 6;                 // 0..3
    const int bn   = box_ind[n];

    // stable bucket rank: slot = #{m: b[m]<bn} + #{m<n: b[m]==bn}
    #pragma unroll
    for (int r = 0; r < 2; ++r) {
        const int m  = r * 256 + t;          // covers 0..511
        const int bm = box_ind[m];
        const unsigned long long lt = __ballot(bm < bn);
        const unsigned long long eq = __ballot(bm == bn);
        const int rel = n - (r * 256 + wv * 64);
        const unsigned long long pre =
            (rel <= 0) ? 0ull : ((rel >= 64) ? ~0ull : ((1ull << rel) - 1ull));
        if (lane == 0) {
            s_lt[wv * 2 + r] = __popcll(lt);
            s_eq[wv * 2 + r] = __popcll(eq & pre);
        }
    }
    __syncthreads();
    int slot = 0;
    #pragma unroll
    for (int i = 0; i < 8; ++i) slot += s_lt[i] + s_eq[i];

    if (t >= CROP_HW) return;
    const int h = t / CROP_W;
    const int w = t - h * CROP_W;

    const float4 bx = reinterpret_cast<const float4*>(boxes)[n];
    const float y1 = bx.x, x1 = bx.y, y2 = bx.z, x2 = bx.w;

    const float scale_y = (y2 - y1) * (float)(IMG_H - 1) / (float)(CROP_H - 1);
    const float scale_x = (x2 - x1) * (float)(IMG_W - 1) / (float)(CROP_W - 1);

    const float in_y = y1 * (float)(IMG_H - 1) + (float)h * scale_y;
    const float in_x = x1 * (float)(IMG_W - 1) + (float)w * scale_x;

    const bool valid = (in_y >= 0.0f) & (in_y <= (float)(IMG_H - 1)) &
                       (in_x >= 0.0f) & (in_x <= (float)(IMG_W - 1));

    const float yc = fminf(fmaxf(in_y, 0.0f), (float)(IMG_H - 1));
    const float xc = fminf(fmaxf(in_x, 0.0f), (float)(IMG_W - 1));

    const float y0f = floorf(yc);
    const float x0f = floorf(xc);
    const float ly = yc - y0f;
    const float lx = xc - x0f;

    const int y0  = (int)y0f;
    const int x0  = (int)x0f;
    const int dy  = min(y0 + 1, IMG_H - 1) - y0;   // 0/1

    const unsigned pk = (unsigned)(y0 * IMG_W + x0)
                      | ((unsigned)dy << 15)
                      | (valid ? (1u << 16) : 0u) | ((unsigned)n << 17);

    const __half2 hh = __floats2half2_rn(lx, ly);
    const unsigned hbits = *reinterpret_cast<const unsigned*>(&hh);

    geo[slot * CROP_HW + t] = make_uint2(pk, hbits);
}

// ---------------- bilinear from fp16 shifted-pair LDS plane ----------------
// sp[o] = half2{ p[o], p[o+1 clamped] }  (4 B/slot -> bank = o % 32, 2-way max)
__device__ __forceinline__ float bilerp_h2(const __half2* __restrict__ sp,
                                           unsigned pk, unsigned hbits)
{
    const int o   = (int)(pk & 0x3FFFu);
    const int dyo = (int)((pk >> 15) & 1u) * IMG_W;
    const __half2 h = *reinterpret_cast<const __half2*>(&hbits);
    const float lx = __low2float(h);
    const float ly = __high2float(h);
    const float wm = (pk & (1u << 16)) ? 1.0f : 0.0f;

    const __half2 tp = sp[o];           // {tl, tr}
    const __half2 bp = sp[o + dyo];     // {bl, br}

    const float tl = __low2float(tp), tr = __high2float(tp);
    const float bl = __low2float(bp), br = __high2float(bp);

    const float top = tl + (tr - tl) * lx;
    const float bot = bl + (br - bl) * lx;
    return (top + (bot - top) * ly) * wm;
}

// ---------------- Kernel 2: one block per (b,c) plane; 512 thr ----------
// Phase order: (1) wave-local sb/nb via ballots, (2) issue ALL geo loads into
// registers (fully unrolled, branchless wrap), (3) stage plane to LDS (the
// pre-barrier vmcnt drain absorbs geo latency), (4) pure LDS+VALU+store loop.
__global__ __launch_bounds__(512, 4) void crop_resize_main(
    const float* __restrict__ image,    // (8, 256, 100, 100)
    const int*   __restrict__ box_ind,  // (512,)
    const uint2* __restrict__ geo,      // sorted by image, n embedded
    float* __restrict__ out)            // (512, 256, 14, 14)
{
    __shared__ __half2 s_pairs[PLANE];  // 40000 B: slot x = {p[x], p[x+1 clamped]}

    const int blk = blockIdx.x;
    const int b   = blk >> 8;
    const int c   = blk & 255;
    const int t   = threadIdx.x;
    const int lane = t & 63;

    // ---- (1) per-wave bucket start/count (no barrier needed) ----
    int sb = 0, nb = 0;
    #pragma unroll
    for (int r = 0; r < 8; ++r) {
        const int bm = box_ind[r * 64 + lane];
        sb += __popcll(__ballot(bm < b));
        nb += __popcll(__ballot(bm == b));
    }

    const int totalq = nb * CROP_HWQ;   // quad units
    const int iters  = (totalq + 511) >> 9;
    const uint4* __restrict__ geo4 =
        reinterpret_cast<const uint4*>(geo) + (size_t)sb * CROP_HWP;

    const float* __restrict__ plane =
        image + ((size_t)(b * NCH + c)) * PLANE;
    const float4* __restrict__ plane_g = reinterpret_cast<const float4*>(plane);
    float* __restrict__ outc = out + (size_t)c * CROP_HW;

    if (totalq >= 512) {
        // ---- (2) hoisted register-resident geo loads, branchless wrap ----
        int  q[MAXI + 1];
        uint4 ga[MAXI], gb[MAXI];
        q[0] = t;
        #pragma unroll
        for (int i = 0; i < MAXI; ++i) {
            const uint4* gp = geo4 + 2 * (size_t)q[i];
            ga[i] = gp[0];
            gb[i] = gp[1];
            const int qn = q[i] + 512;
            q[i + 1] = (qn >= totalq) ? qn - totalq : qn;   // totalq>=512 -> one sub
        }

        // ---- (3) stage shifted fp16 pairs ----
        for (int i = t; i < PLANE / 4; i += 512) {
            const float4 f = plane_g[i];
            const int m    = i % (IMG_W / 4);            // 25 groups per row
            const int base = 4 * i;
            const float nx = plane[base + ((m == (IMG_W / 4 - 1)) ? 3 : 4)];
            s_pairs[base + 0] = __floats2half2_rn(f.x, f.y);
            s_pairs[base + 1] = __floats2half2_rn(f.y, f.z);
            s_pairs[base + 2] = __floats2half2_rn(f.z, f.w);
            s_pairs[base + 3] = __floats2half2_rn(f.w, nx);
        }
        __syncthreads();

        // ---- (4) pure LDS+VALU+store ----
        #pragma unroll
        for (int i = 0; i < MAXI; ++i) {
            if (i < iters) {
                const unsigned n = ga[i].x >> 17;
                const int j = q[i] - (q[i] / CROP_HWQ) * CROP_HWQ;
                float4 val;
                val.x = bilerp_h2(s_pairs, ga[i].x, ga[i].y);
                val.y = bilerp_h2(s_pairs, ga[i].z, ga[i].w);
                val.z = bilerp_h2(s_pairs, gb[i].x, gb[i].y);
                val.w = bilerp_h2(s_pairs, gb[i].z, gb[i].w);
                *reinterpret_cast<float4*>(
                    outc + (size_t)n * (NCH * CROP_HW) + j * 4) = val;
            }
        }
        // rare tail (nb > 83): direct loads
        int qc = q[MAXI];
        for (int it = MAXI; it < iters; ++it) {
            const uint4 a = geo4[2 * qc];
            const uint4 bq = geo4[2 * qc + 1];
            const unsigned n = a.x >> 17;
            const int j = qc - (qc / CROP_HWQ) * CROP_HWQ;
            float4 val;
            val.x = bilerp_h2(s_pairs, a.x, a.y);
            val.y = bilerp_h2(s_pairs, a.z, a.w);
            val.z = bilerp_h2(s_pairs, bq.x, bq.y);
            val.w = bilerp_h2(s_pairs, bq.z, bq.w);
            *reinterpret_cast<float4*>(
                outc + (size_t)n * (NCH * CROP_HW) + j * 4) = val;
            const int qn = qc + 512;
            qc = (qn >= totalq) ? qn - totalq : qn;
        }
    } else {
        // generic path (tiny buckets): stage then simple strided loop
        for (int i = t; i < PLANE / 4; i += 512) {
            const float4 f = plane_g[i];
            const int m    = i % (IMG_W / 4);
            const int base = 4 * i;
            const float nx = plane[base + ((m == (IMG_W / 4 - 1)) ? 3 : 4)];
            s_pairs[base + 0] = __floats2half2_rn(f.x, f.y);
            s_pairs[base + 1] = __floats2half2_rn(f.y, f.z);
            s_pairs[base + 2] = __floats2half2_rn(f.z, f.w);
            s_pairs[base + 3] = __floats2half2_rn(f.w, nx);
        }
        __syncthreads();
        for (int qc = t; qc < totalq; qc += 512) {
            const uint4 a = geo4[2 * qc];
            const uint4 bq = geo4[2 * qc + 1];
            const unsigned n = a.x >> 17;
            const int j = qc - (qc / CROP_HWQ) * CROP_HWQ;
            float4 val;
            val.x = bilerp_h2(s_pairs, a.x, a.y);
            val.y = bilerp_h2(s_pairs, a.z, a.w);
            val.z = bilerp_h2(s_pairs, bq.x, bq.y);
            val.w = bilerp_h2(s_pairs, bq.z, bq.w);
            *reinterpret_cast<float4*>(
                outc + (size_t)n * (NCH * CROP_HW) + j * 4) = val;
        }
    }
}

// ---------------- Fallback (ws too small): known-good direct kernel ----------------
__global__ __launch_bounds__(256) void crop_resize_simple(
    const float* __restrict__ image, const float* __restrict__ boxes,
    const int* __restrict__ box_ind, float* __restrict__ out)
{
    const int n = blockIdx.y;
    const int i = blockIdx.x * 256 + threadIdx.x;
    const int c  = i / CROP_HW;
    const int hw = i - c * CROP_HW;
    const int h  = hw / CROP_W;
    const int w  = hw - h * CROP_W;

    const float y1 = boxes[n * 4 + 0];
    const float x1 = boxes[n * 4 + 1];
    const float y2 = boxes[n * 4 + 2];
    const float x2 = boxes[n * 4 + 3];
    const int   b  = box_ind[n];

    const float scale_y = (y2 - y1) * (float)(IMG_H - 1) / (float)(CROP_H - 1);
    const float scale_x = (x2 - x1) * (float)(IMG_W - 1) / (float)(CROP_W - 1);
    const float in_y = y1 * (float)(IMG_H - 1) + (float)h * scale_y;
    const float in_x = x1 * (float)(IMG_W - 1) + (float)w * scale_x;
    const bool valid = (in_y >= 0.0f) & (in_y <= (float)(IMG_H - 1)) &
                       (in_x >= 0.0f) & (in_x <= (float)(IMG_W - 1));
    const float yc = fminf(fmaxf(in_y, 0.0f), (float)(IMG_H - 1));
    const float xc = fminf(fmaxf(in_x, 0.0f), (float)(IMG_W - 1));
    const float y0f = floorf(yc), x0f = floorf(xc);
    const float ly = yc - y0f, lx = xc - x0f;
    const int y0 = (int)y0f, x0 = (int)x0f;
    const int y1i = min(y0 + 1, IMG_H - 1), x1i = min(x0 + 1, IMG_W - 1);

    const float* __restrict__ p = image + ((size_t)(b * NCH + c)) * PLANE;
    const float tl = p[y0  * IMG_W + x0];
    const float tr = p[y0  * IMG_W + x1i];
    const float bl = p[y1i * IMG_W + x0];
    const float br = p[y1i * IMG_W + x1i];
    const float top = tl + (tr - tl) * lx;
    const float bot = bl + (br - bl) * lx;
    float val = top + (bot - top) * ly;
    out[(size_t)n * (NCH * CROP_HW) + i] = valid ? val : 0.0f;
}

extern "C" void kernel_launch(void* const* d_in, const int* in_sizes, int n_in,
                              void* d_out, int out_size, void* d_ws, size_t ws_size,
                              hipStream_t stream) {
    const float* image   = (const float*)d_in[0];
    const float* boxes   = (const float*)d_in[1];
    const int*   box_ind = (const int*)d_in[2];
    float* out = (float*)d_out;

    if (ws_size < WS_NEED) {
        dim3 grid(196, NBOX);
        crop_resize_simple<<<grid, dim3(256), 0, stream>>>(image, boxes, box_ind, out);
        return;
    }

    uint2* geo = (uint2*)d_ws;

    geom_kernel<<<dim3(NBOX), dim3(256), 0, stream>>>(boxes, box_ind, geo);
    crop_resize_main<<<dim3(NIMG * NCH), dim3(512), 0, stream>>>(image, box_ind, geo, out);
}

// Round 14
// 40.021 us; speedup vs baseline: 1.1628x; 1.1628x over previous
//
#include <hip/hip_runtime.h>
#include <hip/hip_fp16.h>

#define CROP_H 14
#define CROP_W 14
#define CROP_HW 196
#define CROP_HWP 98          // uint4 (pair) units per box
#define CROP_HWQ 49          // quad units per box
#define IMG_H 100
#define IMG_W 100
#define PLANE 10000
#define NCH 256
#define NBOX 512
#define NIMG 8

// d_ws layout: geo_sorted : uint2[NBOX*CROP_HW] (8 B per (slot,hw), sorted by image)
#define GEO_BYTES ((size_t)NBOX * CROP_HW * 8)
#define WS_NEED   GEO_BYTES

// ---------------- Kernel 1: geometry, self-computed stable slot, n embedded ------
// pk bits: [13:0]=tl offset (y0*100+x0), [14]=dx, [15]=dy, [16]=valid, [25:17]=n
__global__ __launch_bounds__(256) void geom_kernel(
    const float* __restrict__ boxes, const int* __restrict__ box_ind,
    uint2* __restrict__ geo)
{
    __shared__ int s_lt[8], s_eq[8];

    const int n    = blockIdx.x;
    const int t    = threadIdx.x;
    const int lane = t & 63;
    const int wv   = t >> 6;                 // 0..3
    const int bn   = box_ind[n];

    // stable bucket rank: slot = #{m: b[m]<bn} + #{m<n: b[m]==bn}
    #pragma unroll
    for (int r = 0; r < 2; ++r) {
        const int m  = r * 256 + t;          // covers 0..511
        const int bm = box_ind[m];
        const unsigned long long lt = __ballot(bm < bn);
        const unsigned long long eq = __ballot(bm == bn);
        const int rel = n - (r * 256 + wv * 64);
        const unsigned long long pre =
            (rel <= 0) ? 0ull : ((rel >= 64) ? ~0ull : ((1ull << rel) - 1ull));
        if (lane == 0) {
            s_lt[wv * 2 + r] = __popcll(lt);
            s_eq[wv * 2 + r] = __popcll(eq & pre);
        }
    }
    __syncthreads();
    int slot = 0;
    #pragma unroll
    for (int i = 0; i < 8; ++i) slot += s_lt[i] + s_eq[i];

    if (t >= CROP_HW) return;
    const int h = t / CROP_W;
    const int w = t - h * CROP_W;

    const float4 bx = reinterpret_cast<const float4*>(boxes)[n];
    const float y1 = bx.x, x1 = bx.y, y2 = bx.z, x2 = bx.w;

    const float scale_y = (y2 - y1) * (float)(IMG_H - 1) / (float)(CROP_H - 1);
    const float scale_x = (x2 - x1) * (float)(IMG_W - 1) / (float)(CROP_W - 1);

    const float in_y = y1 * (float)(IMG_H - 1) + (float)h * scale_y;
    const float in_x = x1 * (float)(IMG_W - 1) + (float)w * scale_x;

    const bool valid = (in_y >= 0.0f) & (in_y <= (float)(IMG_H - 1)) &
                       (in_x >= 0.0f) & (in_x <= (float)(IMG_W - 1));

    const float yc = fminf(fmaxf(in_y, 0.0f), (float)(IMG_H - 1));
    const float xc = fminf(fmaxf(in_x, 0.0f), (float)(IMG_W - 1));

    const float y0f = floorf(yc);
    const float x0f = floorf(xc);
    const float ly = yc - y0f;
    const float lx = xc - x0f;

    const int y0  = (int)y0f;
    const int x0  = (int)x0f;
    const int dy  = min(y0 + 1, IMG_H - 1) - y0;   // 0/1
    const int dx  = min(x0 + 1, IMG_W - 1) - x0;   // 0/1

    const unsigned pk = (unsigned)(y0 * IMG_W + x0)
                      | ((unsigned)dx << 14) | ((unsigned)dy << 15)
                      | (valid ? (1u << 16) : 0u) | ((unsigned)n << 17);

    const __half2 hh = __floats2half2_rn(lx, ly);
    const unsigned hbits = *reinterpret_cast<const unsigned*>(&hh);

    geo[slot * CROP_HW + t] = make_uint2(pk, hbits);
}

// ---------------- dual-channel bilinear from fp16 channel-pair LDS ----------------
// sp[x] = half2{ c0[x], c1[x] }  (4 B/slot -> bank = x % 32, 2-way max)
// returns {val_c0, val_c1} for one (n,hw)
__device__ __forceinline__ float2 bilerp_du(const __half2* __restrict__ sp,
                                            unsigned pk, unsigned hbits)
{
    const int o   = (int)(pk & 0x3FFFu);
    const int dx  = (int)((pk >> 14) & 1u);
    const int dyo = (int)((pk >> 15) & 1u) * IMG_W;
    const __half2 h = *reinterpret_cast<const __half2*>(&hbits);
    const float lx = __low2float(h);
    const float ly = __high2float(h);
    const float wm = (pk & (1u << 16)) ? 1.0f : 0.0f;

    const __half2 tl2 = sp[o];
    const __half2 tr2 = sp[o + dx];
    const __half2 bl2 = sp[o + dyo];
    const __half2 br2 = sp[o + dyo + dx];

    const float tl0 = __low2float(tl2),  tl1 = __high2float(tl2);
    const float tr0 = __low2float(tr2),  tr1 = __high2float(tr2);
    const float bl0 = __low2float(bl2),  bl1 = __high2float(bl2);
    const float br0 = __low2float(br2),  br1 = __high2float(br2);

    const float top0 = tl0 + (tr0 - tl0) * lx;
    const float bot0 = bl0 + (br0 - bl0) * lx;
    const float top1 = tl1 + (tr1 - tl1) * lx;
    const float bot1 = bl1 + (br1 - bl1) * lx;

    float2 r;
    r.x = (top0 + (bot0 - top0) * ly) * wm;
    r.y = (top1 + (bot1 - top1) * ly) * wm;
    return r;
}

// ---------------- Kernel 2: one block per (b, channel-PAIR); 512 thr ----------
// Each 4-tap LDS gather serves TWO channels; geo loads & staging amortized 2x.
__global__ __launch_bounds__(512, 4) void crop_resize_main(
    const float* __restrict__ image,    // (8, 256, 100, 100)
    const int*   __restrict__ box_ind,  // (512,)
    const uint2* __restrict__ geo,      // sorted by image, n embedded
    float* __restrict__ out)            // (512, 256, 14, 14)
{
    __shared__ __half2 s_du[PLANE];     // 40000 B: slot x = {c0[x], c1[x]}

    const int blk = blockIdx.x;
    const int b   = blk >> 7;           // 0..7
    const int cp  = blk & 127;          // channel pair 0..127
    const int c0  = cp * 2;
    const int t   = threadIdx.x;
    const int lane = t & 63;

    // ---- per-wave bucket start/count via ballots (no LDS, no barrier) ----
    int sb = 0, nb = 0;
    #pragma unroll
    for (int r = 0; r < 8; ++r) {
        const int bm = box_ind[r * 64 + lane];
        sb += __popcll(__ballot(bm < b));
        nb += __popcll(__ballot(bm == b));
    }

    // ---- stage two planes as channel-pair half2 (no shifted duplication) ----
    const float* __restrict__ p0 = image + ((size_t)(b * NCH + c0)) * PLANE;
    const float4* __restrict__ p0g = reinterpret_cast<const float4*>(p0);
    const float4* __restrict__ p1g = reinterpret_cast<const float4*>(p0 + PLANE);

    for (int i = t; i < PLANE / 4; i += 512) {
        const float4 f0 = p0g[i];
        const float4 f1 = p1g[i];
        const int base = 4 * i;
        s_du[base + 0] = __floats2half2_rn(f0.x, f1.x);
        s_du[base + 1] = __floats2half2_rn(f0.y, f1.y);
        s_du[base + 2] = __floats2half2_rn(f0.z, f1.z);
        s_du[base + 3] = __floats2half2_rn(f0.w, f1.w);
    }
    __syncthreads();

    const int totalq = nb * CROP_HWQ;   // quad units (each serves both channels)
    if (totalq == 0) return;

    const uint4* __restrict__ geo4 =
        reinterpret_cast<const uint4*>(geo) + (size_t)sb * CROP_HWP;
    float* __restrict__ outc = out + (size_t)c0 * CROP_HW;

    // branchless wrap-around loop: duplicate quads write identical bytes (benign)
    int q = t;
    while (q >= totalq) q -= totalq;
    uint4 ga = geo4[2 * q];
    uint4 gb = geo4[2 * q + 1];

    const int iters = (totalq + 511) >> 9;
    for (int it = 0; it < iters; ++it) {
        int qn = q + 512;
        while (qn >= totalq) qn -= totalq;
        const uint4 gna = geo4[2 * qn];       // prefetch next iteration
        const uint4 gnb = geo4[2 * qn + 1];

        const unsigned n = ga.x >> 17;
        const int j = q - (q / CROP_HWQ) * CROP_HWQ;

        const float2 r0 = bilerp_du(s_du, ga.x, ga.y);
        const float2 r1 = bilerp_du(s_du, ga.z, ga.w);
        const float2 r2 = bilerp_du(s_du, gb.x, gb.y);
        const float2 r3 = bilerp_du(s_du, gb.z, gb.w);

        float* dst = outc + (size_t)n * (NCH * CROP_HW) + j * 4;
        *reinterpret_cast<float4*>(dst) = make_float4(r0.x, r1.x, r2.x, r3.x);
        *reinterpret_cast<float4*>(dst + CROP_HW) = make_float4(r0.y, r1.y, r2.y, r3.y);

        q = qn; ga = gna; gb = gnb;
    }
}

// ---------------- Fallback (ws too small): known-good direct kernel ----------------
__global__ __launch_bounds__(256) void crop_resize_simple(
    const float* __restrict__ image, const float* __restrict__ boxes,
    const int* __restrict__ box_ind, float* __restrict__ out)
{
    const int n = blockIdx.y;
    const int i = blockIdx.x * 256 + threadIdx.x;
    const int c  = i / CROP_HW;
    const int hw = i - c * CROP_HW;
    const int h  = hw / CROP_W;
    const int w  = hw - h * CROP_W;

    const float y1 = boxes[n * 4 + 0];
    const float x1 = boxes[n * 4 + 1];
    const float y2 = boxes[n * 4 + 2];
    const float x2 = boxes[n * 4 + 3];
    const int   b  = box_ind[n];

    const float scale_y = (y2 - y1) * (float)(IMG_H - 1) / (float)(CROP_H - 1);
    const float scale_x = (x2 - x1) * (float)(IMG_W - 1) / (float)(CROP_W - 1);
    const float in_y = y1 * (float)(IMG_H - 1) + (float)h * scale_y;
    const float in_x = x1 * (float)(IMG_W - 1) + (float)w * scale_x;
    const bool valid = (in_y >= 0.0f) & (in_y <= (float)(IMG_H - 1)) &
                       (in_x >= 0.0f) & (in_x <= (float)(IMG_W - 1));
    const float yc = fminf(fmaxf(in_y, 0.0f), (float)(IMG_H - 1));
    const float xc = fminf(fmaxf(in_x, 0.0f), (float)(IMG_W - 1));
    const float y0f = floorf(yc), x0f = floorf(xc);
    const float ly = yc - y0f, lx = xc - x0f;
    const int y0 = (int)y0f, x0 = (int)x0f;
    const int y1i = min(y0 + 1, IMG_H - 1), x1i = min(x0 + 1, IMG_W - 1);

    const float* __restrict__ p = image + ((size_t)(b * NCH + c)) * PLANE;
    const float tl = p[y0  * IMG_W + x0];
    const float tr = p[y0  * IMG_W + x1i];
    const float bl = p[y1i * IMG_W + x0];
    const float br = p[y1i * IMG_W + x1i];
    const float top = tl + (tr - tl) * lx;
    const float bot = bl + (br - bl) * lx;
    float val = top + (bot - top) * ly;
    out[(size_t)n * (NCH * CROP_HW) + i] = valid ? val : 0.0f;
}

extern "C" void kernel_launch(void* const* d_in, const int* in_sizes, int n_in,
                              void* d_out, int out_size, void* d_ws, size_t ws_size,
                              hipStream_t stream) {
    const float* image   = (const float*)d_in[0];
    const float* boxes   = (const float*)d_in[1];
    const int*   box_ind = (const int*)d_in[2];
    float* out = (float*)d_out;

    if (ws_size < WS_NEED) {
        dim3 grid(196, NBOX);
        crop_resize_simple<<<grid, dim3(256), 0, stream>>>(image, boxes, box_ind, out);
        return;
    }

    uint2* geo = (uint2*)d_ws;

    geom_kernel<<<dim3(NBOX), dim3(256), 0, stream>>>(boxes, box_ind, geo);
    crop_resize_main<<<dim3(NIMG * (NCH / 2)), dim3(512), 0, stream>>>(image, box_ind, geo, out);
}

// Round 15
// 38.982 us; speedup vs baseline: 1.1938x; 1.0267x over previous
//
#include <hip/hip_runtime.h>
#include <hip/hip_fp16.h>

#define CROP_H 14
#define CROP_W 14
#define CROP_HW 196
#define CROP_HWQ 49          // quad units per box
#define IMG_H 100
#define IMG_W 100
#define PLANE 10000
#define NCH 256
#define NBOX 512
#define NIMG 8

// ---------------- fused single kernel: one block per (b, channel-pair) ----------
// Phase 1: ballot-scan builds per-image box list + per-box geometry scalars in LDS.
// Phase 2: stage the two channel planes as half2{c0,c1} (4 B/slot, conflict-free).
// Phase 3: hot loop with ZERO global loads: inline geometry (VALU) -> 4 LDS taps
//          serving two channels -> coalesced float4 stores.
__global__ __launch_bounds__(512, 4) void crop_resize_fused(
    const float* __restrict__ image,    // (8, 256, 100, 100)
    const float* __restrict__ boxes,    // (512, 4)
    const int*   __restrict__ box_ind,  // (512,)
    float* __restrict__ out)            // (512, 256, 14, 14)
{
    __shared__ __half2 s_du[PLANE];     // 40000 B: slot x = {c0[x], c1[x]}
    __shared__ float4  s_bgeo[NBOX];    // {ybase, ystep, xbase, xstep} per bucket slot
    __shared__ int     s_perm[NBOX];    // bucket slot -> box id n
    __shared__ int     s_eqw[8];        // per-wave bucket-membership counts

    const int blk  = blockIdx.x;
    const int b    = blk >> 7;          // image 0..7
    const int cp   = blk & 127;         // channel pair 0..127
    const int c0   = cp * 2;
    const int t    = threadIdx.x;
    const int lane = t & 63;
    const int wv   = t >> 6;            // 0..7

    // ---- phase 1a: membership ballot (t covers all 512 boxes) ----
    const int bn_t = box_ind[t];
    const bool mine = (bn_t == b);
    const unsigned long long eq = __ballot(mine);
    if (lane == 0) s_eqw[wv] = __popcll(eq);
    const int pre = __popcll(eq & ((lane == 0) ? 0ull : ((1ull << lane) - 1ull)));

    // ---- phase 2: stage two planes as channel-pair half2 ----
    const float* __restrict__ p0 = image + ((size_t)(b * NCH + c0)) * PLANE;
    const float4* __restrict__ p0g = reinterpret_cast<const float4*>(p0);
    const float4* __restrict__ p1g = reinterpret_cast<const float4*>(p0 + PLANE);

    for (int i = t; i < PLANE / 4; i += 512) {
        const float4 f0 = p0g[i];
        const float4 f1 = p1g[i];
        const int base = 4 * i;
        s_du[base + 0] = __floats2half2_rn(f0.x, f1.x);
        s_du[base + 1] = __floats2half2_rn(f0.y, f1.y);
        s_du[base + 2] = __floats2half2_rn(f0.z, f1.z);
        s_du[base + 3] = __floats2half2_rn(f0.w, f1.w);
    }
    __syncthreads();

    // ---- phase 1b: build perm + per-box geometry scalars ----
    int basecnt = 0, nb = 0;
    #pragma unroll
    for (int i = 0; i < 8; ++i) {
        const int cwv = s_eqw[i];
        if (i < wv) basecnt += cwv;
        nb += cwv;
    }
    if (mine) {
        const int r = basecnt + pre;
        s_perm[r] = t;
        const float4 bx = reinterpret_cast<const float4*>(boxes)[t];
        float4 g;
        g.x = bx.x * (float)(IMG_H - 1);                                  // ybase
        g.y = (bx.z - bx.x) * (float)(IMG_H - 1) / (float)(CROP_H - 1);   // ystep
        g.z = bx.y * (float)(IMG_W - 1);                                  // xbase
        g.w = (bx.w - bx.y) * (float)(IMG_W - 1) / (float)(CROP_W - 1);   // xstep
        s_bgeo[r] = g;
    }
    __syncthreads();

    const int totalq = nb * CROP_HWQ;
    float* __restrict__ outc = out + (size_t)c0 * CROP_HW;

    // ---- phase 3: pure LDS+VALU+store hot loop ----
    for (int q = t; q < totalq; q += 512) {
        const int bl = q / CROP_HWQ;            // magic-mul
        const int j  = q - bl * CROP_HWQ;       // quad index 0..48
        const int n  = s_perm[bl];              // broadcast-ish LDS read
        const float4 g = s_bgeo[bl];            // broadcast-ish LDS read

        float vals0[4], vals1[4];
        #pragma unroll
        for (int k = 0; k < 4; ++k) {
            const int hw = j * 4 + k;
            const int h  = hw / CROP_W;         // magic-mul
            const int w  = hw - h * CROP_W;

            const float in_y = g.x + (float)h * g.y;
            const float in_x = g.z + (float)w * g.w;

            const bool valid = (in_y >= 0.0f) & (in_y <= (float)(IMG_H - 1)) &
                               (in_x >= 0.0f) & (in_x <= (float)(IMG_W - 1));

            const float yc = fminf(fmaxf(in_y, 0.0f), (float)(IMG_H - 1));
            const float xc = fminf(fmaxf(in_x, 0.0f), (float)(IMG_W - 1));

            const float y0f = floorf(yc);
            const float x0f = floorf(xc);
            const float ly = yc - y0f;
            const float lx = xc - x0f;

            const int y0  = (int)y0f;
            const int x0  = (int)x0f;
            const int dx  = min(x0 + 1, IMG_W - 1) - x0;   // 0/1
            const int dyo = (min(y0 + 1, IMG_H - 1) - y0) * IMG_W;

            const int o = y0 * IMG_W + x0;

            const __half2 tl2 = s_du[o];
            const __half2 tr2 = s_du[o + dx];
            const __half2 bl2 = s_du[o + dyo];
            const __half2 br2 = s_du[o + dyo + dx];

            const float wm = valid ? 1.0f : 0.0f;

            const float tl0 = __low2float(tl2),  tl1 = __high2float(tl2);
            const float tr0 = __low2float(tr2),  tr1 = __high2float(tr2);
            const float bl0 = __low2float(bl2),  bl1 = __high2float(bl2);
            const float br0 = __low2float(br2),  br1 = __high2float(br2);

            const float top0 = tl0 + (tr0 - tl0) * lx;
            const float bot0 = bl0 + (br0 - bl0) * lx;
            const float top1 = tl1 + (tr1 - tl1) * lx;
            const float bot1 = bl1 + (br1 - bl1) * lx;

            vals0[k] = (top0 + (bot0 - top0) * ly) * wm;
            vals1[k] = (top1 + (bot1 - top1) * ly) * wm;
        }

        float* dst = outc + (size_t)n * (NCH * CROP_HW) + j * 4;
        *reinterpret_cast<float4*>(dst) =
            make_float4(vals0[0], vals0[1], vals0[2], vals0[3]);
        *reinterpret_cast<float4*>(dst + CROP_HW) =
            make_float4(vals1[0], vals1[1], vals1[2], vals1[3]);
    }
}

extern "C" void kernel_launch(void* const* d_in, const int* in_sizes, int n_in,
                              void* d_out, int out_size, void* d_ws, size_t ws_size,
                              hipStream_t stream) {
    const float* image   = (const float*)d_in[0];
    const float* boxes   = (const float*)d_in[1];
    const int*   box_ind = (const int*)d_in[2];
    float* out = (float*)d_out;

    crop_resize_fused<<<dim3(NIMG * (NCH / 2)), dim3(512), 0, stream>>>(
        image, boxes, box_ind, out);
}